// Round 1
// baseline (576.408 us; speedup 1.0000x reference)
//
#include <hip/hip_runtime.h>
#include <math.h>

#define N 4096
#define BH 8
#define THREADS 256
#define PARTS 32              // rank blocks per row -> BH*PARTS = 256 blocks (1/CU)
#define EPB 128               // elements ranked per block
#define EPT 4                 // elements per thread
#define SLICES 8              // key slices per row scan
#define KPS (N / SLICES)      // 512 keys per slice
#define CHUNK (N / THREADS)   // 16 sorted positions per thread in scan phase
#define FILL_BLOCKS 2048      // 8 blocks/CU -> 32 waves/CU, full occupancy
#define FILL_ITERS 64         // (BH*N*N/4) / (FILL_BLOCKS*THREADS) = 64 exactly

typedef float f32x4 __attribute__((ext_vector_type(4)));  // clang vector: OK for
                                                          // __builtin_nontemporal_store

// Monotone-descending stable composite key: ascending u64 order of
// (desc_bits(r*100) << 32 | index) == stable descending sort of r*100
// (matches reference argsort(-r*100, stable) exactly, including f32-multiply
// ties; indices are distinct so ONE u64 compare encodes the full
// lexicographic (key, index) order).
__device__ __forceinline__ unsigned long long desc_key64(float r, int i) {
    float k = r * 100.0f;
    unsigned int b = __float_as_uint(k);
    unsigned int asc = (b & 0x80000000u) ? ~b : (b | 0x80000000u);
    return ((unsigned long long)(~asc) << 32) | (unsigned int)i;
}

// ---------------------------------------------------------------------------
// Kernel 1: rank-by-counting with u64 keys (unchanged — ~10 us, 2 VALU ops
// per comparison, ds_read_b128 amortized over 4 elements).
// Scatter: cols[rank] = e, rsort[rank] = r[e]  (ranks are a permutation).
// ---------------------------------------------------------------------------
__global__ __launch_bounds__(THREADS)
void rank_kernel(const float* __restrict__ ranking,
                 int* __restrict__ cols,
                 float* __restrict__ rsort) {
    __shared__ unsigned long long keys[N];               // 32 KB
    __shared__ unsigned short partial[SLICES * EPB];     // 2 KB

    const int bh   = blockIdx.x / PARTS;
    const int part = blockIdx.x % PARTS;
    const float* r = ranking + (size_t)bh * N;

    const float4* r4 = (const float4*)r;
    for (int i = threadIdx.x; i < N / 4; i += THREADS) {
        float4 w = r4[i];
        keys[i * 4 + 0] = desc_key64(w.x, i * 4 + 0);
        keys[i * 4 + 1] = desc_key64(w.y, i * 4 + 1);
        keys[i * 4 + 2] = desc_key64(w.z, i * 4 + 2);
        keys[i * 4 + 3] = desc_key64(w.w, i * 4 + 3);
    }
    __syncthreads();

    const int g = threadIdx.x & 31;
    const int s = threadIdx.x >> 5;
    const int e_base = g * EPT;

    unsigned long long mykey[EPT];
    #pragma unroll
    for (int j = 0; j < EPT; ++j)
        mykey[j] = keys[part * EPB + e_base + j];

    int cnt0 = 0, cnt1 = 0, cnt2 = 0, cnt3 = 0;
    const ulonglong2* k2 = (const ulonglong2*)(keys + s * KPS);
    #pragma unroll 4
    for (int k = 0; k < KPS / 2; ++k) {
        ulonglong2 kk = k2[k];
        cnt0 += (kk.x < mykey[0]) + (kk.y < mykey[0]);
        cnt1 += (kk.x < mykey[1]) + (kk.y < mykey[1]);
        cnt2 += (kk.x < mykey[2]) + (kk.y < mykey[2]);
        cnt3 += (kk.x < mykey[3]) + (kk.y < mykey[3]);
    }
    partial[s * EPB + e_base + 0] = (unsigned short)cnt0;
    partial[s * EPB + e_base + 1] = (unsigned short)cnt1;
    partial[s * EPB + e_base + 2] = (unsigned short)cnt2;
    partial[s * EPB + e_base + 3] = (unsigned short)cnt3;
    __syncthreads();

    if (threadIdx.x < EPB) {
        int rank = 0;
        #pragma unroll
        for (int t = 0; t < SLICES; ++t)
            rank += (int)partial[t * EPB + threadIdx.x];
        int e = part * EPB + threadIdx.x;
        size_t o = (size_t)bh * N + rank;
        cols[o]  = e;
        rsort[o] = r[e];
    }
}

// ---------------------------------------------------------------------------
// Kernel 2: pure zero-fill of the 512 MiB output. Structurally identical to
// rocclr's fillBufferAligned, which this capture shows at 6.33 TB/s. No
// barriers, no f64 state, no per-store predicate — nothing interleaved into
// the store stream. Nontemporal: 512 MiB >> 32 MB L2, don't dirty it.
// ---------------------------------------------------------------------------
__global__ __launch_bounds__(THREADS)
void zero_kernel(float* __restrict__ out) {
    f32x4 z = {0.f, 0.f, 0.f, 0.f};
    f32x4* o = (f32x4*)out;
    size_t i = (size_t)blockIdx.x * THREADS + threadIdx.x;
    const size_t stride = (size_t)FILL_BLOCKS * THREADS;
    #pragma unroll 8
    for (int k = 0; k < FILL_ITERS; ++k) {
        __builtin_nontemporal_store(z, o + i);
        i += stride;
    }
}

// ---------------------------------------------------------------------------
// Kernel 3: scan + scatter, computed ONCE per bh row (8 blocks total) instead
// of 512x redundantly. Per-thread f64 inclusive prefix over its 16 positions,
// Hillis-Steele scan of the 256 chunk sums, then each thread computes its 16
// perm values and scatters them (plain dword stores; ~32K lines = ~4 MB of
// traffic). Runs after zero_kernel in stream order. Math is bit-identical to
// the previous fused kernel: indicator clamped >= 0 BEFORE exp so arg <= 0 ->
// val in (0,1], never inf/NaN (ref overflows to +inf where indicator stays
// negative after the single +n wrap; inf in our buffer would give inf-inf=NaN
// in the comparator).
// ---------------------------------------------------------------------------
__global__ __launch_bounds__(THREADS)
void scanscatter_kernel(const int* __restrict__ cols,
                        const float* __restrict__ rsort,
                        float* __restrict__ out) {
    __shared__ double sdata[THREADS];

    const int tid  = threadIdx.x;
    const int bh   = blockIdx.x;
    const int base = tid * CHUNK;

    // Column indices for my 16 sorted positions (latency hidden by scan below)
    int c[CHUNK];
    const int4* c4 = (const int4*)(cols + (size_t)bh * N + base);
    #pragma unroll
    for (int q = 0; q < CHUNK / 4; ++q) {
        int4 w = c4[q];
        c[q * 4 + 0] = w.x; c[q * 4 + 1] = w.y;
        c[q * 4 + 2] = w.z; c[q * 4 + 3] = w.w;
    }

    // Per-thread local inclusive prefix over CHUNK=16 positions
    const float* rs = rsort + (size_t)bh * N;
    float  v[CHUNK];
    double local[CHUNK];
    const float4* f4 = (const float4*)(rs + base);
    #pragma unroll
    for (int q = 0; q < CHUNK / 4; ++q) {
        float4 w = f4[q];
        v[q * 4 + 0] = w.x; v[q * 4 + 1] = w.y;
        v[q * 4 + 2] = w.z; v[q * 4 + 3] = w.w;
    }
    double ssum = 0.0;
    #pragma unroll
    for (int q = 0; q < CHUNK; ++q) { ssum += (double)v[q]; local[q] = ssum; }

    // Hillis-Steele inclusive scan of the 256 chunk sums -> exclusive offset
    sdata[tid] = ssum;
    __syncthreads();
    #pragma unroll
    for (int s = 1; s < THREADS; s <<= 1) {
        double y = (tid >= s) ? sdata[tid - s] : 0.0;
        __syncthreads();
        sdata[tid] += y;
        __syncthreads();
    }
    const double off = sdata[tid] - ssum;    // sum of chunk sums [0..tid)

    float* obase = out + (size_t)bh * N * N;
    #pragma unroll
    for (int q = 0; q < CHUNK; ++q) {
        int i = base + q;                    // sorted position == output row
        double cumsum = off + local[q];
        double rel    = cumsum - (double)(i + 1) * (double)v[q];
        double rank   = rel > 0.0 ? rel : 0.0;  // relu
        double ind    = (double)i - rank;
        if (ind < 0.0) ind += (double)N;     // reference's single wrap
        if (ind < 0.0) ind = 0.0;            // ref is inf here; stay finite
        obase[(size_t)i * N + c[q]] = (float)exp(ind * -10.0);
    }
}

extern "C" void kernel_launch(void* const* d_in, const int* in_sizes, int n_in,
                              void* d_out, int out_size, void* d_ws, size_t ws_size,
                              hipStream_t stream) {
    const float* ranking = (const float*)d_in[0];
    float* out = (float*)d_out;

    // Workspace layout: cols[BH*N] ints, rsort[BH*N] floats
    int*   cols  = (int*)d_ws;
    float* rsort = (float*)((char*)d_ws + sizeof(int) * (size_t)BH * N);

    rank_kernel<<<BH * PARTS, THREADS, 0, stream>>>(ranking, cols, rsort);
    zero_kernel<<<FILL_BLOCKS, THREADS, 0, stream>>>(out);
    scanscatter_kernel<<<BH, THREADS, 0, stream>>>(cols, rsort, out);
}

// Round 3
// 562.236 us; speedup vs baseline: 1.0252x; 1.0252x over previous
//
#include <hip/hip_runtime.h>
#include <math.h>

#define N 4096
#define BH 8
#define THREADS 256
#define PARTS 32              // rank blocks per row -> BH*PARTS = 256 rank blocks
#define EPB 128               // elements ranked per block
#define EPT 4                 // elements per thread
#define SLICES 8              // key slices per row scan
#define KPS (N / SLICES)      // 512 keys per slice
#define CHUNK (N / THREADS)   // 16 sorted positions per thread in scan phase
#define ZERO_BLOCKS 2048      // 8 blocks/CU -> full occupancy
#define FILL_ITERS 64         // (BH*N*N/4) / (ZERO_BLOCKS*THREADS) = 64 exactly

typedef float f32x4 __attribute__((ext_vector_type(4)));

// Monotone-descending stable composite key: ascending u64 order of
// (desc_bits(r*100) << 32 | index) == stable descending sort of r*100
// (matches reference argsort(-r*100, stable) exactly, including f32-multiply
// ties; indices are distinct so ONE u64 compare encodes the full
// lexicographic (key, index) order).
__device__ __forceinline__ unsigned long long desc_key64(float r, int i) {
    float k = r * 100.0f;
    unsigned int b = __float_as_uint(k);
    unsigned int asc = (b & 0x80000000u) ? ~b : (b | 0x80000000u);
    return ((unsigned long long)(~asc) << 32) | (unsigned int)i;
}

// ---------------------------------------------------------------------------
// Kernel 1: rank-by-counting with u64 keys (unchanged from the 537us R0
// baseline — ~10 us). Scatter: cols[rank] = e, rsort[rank] = r[e].
// ---------------------------------------------------------------------------
__global__ __launch_bounds__(THREADS)
void rank_kernel(const float* __restrict__ ranking,
                 int* __restrict__ cols,
                 float* __restrict__ rsort) {
    __shared__ unsigned long long keys[N];               // 32 KB
    __shared__ unsigned short partial[SLICES * EPB];     // 2 KB

    const int bh   = blockIdx.x / PARTS;
    const int part = blockIdx.x % PARTS;
    const float* r = ranking + (size_t)bh * N;

    const float4* r4 = (const float4*)r;
    for (int i = threadIdx.x; i < N / 4; i += THREADS) {
        float4 w = r4[i];
        keys[i * 4 + 0] = desc_key64(w.x, i * 4 + 0);
        keys[i * 4 + 1] = desc_key64(w.y, i * 4 + 1);
        keys[i * 4 + 2] = desc_key64(w.z, i * 4 + 2);
        keys[i * 4 + 3] = desc_key64(w.w, i * 4 + 3);
    }
    __syncthreads();

    const int g = threadIdx.x & 31;
    const int s = threadIdx.x >> 5;
    const int e_base = g * EPT;

    unsigned long long mykey[EPT];
    #pragma unroll
    for (int j = 0; j < EPT; ++j)
        mykey[j] = keys[part * EPB + e_base + j];

    int cnt0 = 0, cnt1 = 0, cnt2 = 0, cnt3 = 0;
    const ulonglong2* k2 = (const ulonglong2*)(keys + s * KPS);
    #pragma unroll 4
    for (int k = 0; k < KPS / 2; ++k) {
        ulonglong2 kk = k2[k];
        cnt0 += (kk.x < mykey[0]) + (kk.y < mykey[0]);
        cnt1 += (kk.x < mykey[1]) + (kk.y < mykey[1]);
        cnt2 += (kk.x < mykey[2]) + (kk.y < mykey[2]);
        cnt3 += (kk.x < mykey[3]) + (kk.y < mykey[3]);
    }
    partial[s * EPB + e_base + 0] = (unsigned short)cnt0;
    partial[s * EPB + e_base + 1] = (unsigned short)cnt1;
    partial[s * EPB + e_base + 2] = (unsigned short)cnt2;
    partial[s * EPB + e_base + 3] = (unsigned short)cnt3;
    __syncthreads();

    if (threadIdx.x < EPB) {
        int rank = 0;
        #pragma unroll
        for (int t = 0; t < SLICES; ++t)
            rank += (int)partial[t * EPB + threadIdx.x];
        int e = part * EPB + threadIdx.x;
        size_t o = (size_t)bh * N + rank;
        cols[o]  = e;
        rsort[o] = r[e];
    }
}

// ---------------------------------------------------------------------------
// Kernel 2: pure zero-fill of the 512 MiB output with PLAIN float4 stores —
// NO nontemporal flag. A/B evidence (R0/R1): rocclr's plain-store
// fillBufferAligned does 6.2 TB/s on this same arena while both of our
// nt-store kernels sat at ~2.6-2.9 TB/s effective; on gfx950 the L2
// write-allocate + full-line dirty-eviction path is the fast write path,
// the nt/no-allocate bypass is the slow one.
// ---------------------------------------------------------------------------
__global__ __launch_bounds__(THREADS)
void zero_kernel(float* __restrict__ out) {
    f32x4 z = {0.f, 0.f, 0.f, 0.f};
    f32x4* o = (f32x4*)out;
    size_t i = (size_t)blockIdx.x * THREADS + threadIdx.x;
    const size_t stride = (size_t)ZERO_BLOCKS * THREADS;
    #pragma unroll 8
    for (int k = 0; k < FILL_ITERS; ++k) {
        o[i] = z;                         // plain store: L2 write-allocate path
        i += stride;
    }
}

// ---------------------------------------------------------------------------
// Kernel 3: scan + scatter, computed ONCE per bh row (8 blocks total).
// Per-thread f64 inclusive prefix over its 16 positions, Hillis-Steele scan
// of the 256 chunk sums, then each thread computes its 16 perm values and
// scatters them (plain dword stores; ~32K lines). Math is bit-identical to
// the R0 fused kernel: indicator clamped >= 0 BEFORE exp so arg <= 0 ->
// val in (0,1], never inf/NaN (ref overflows to +inf where indicator stays
// negative after the single +n wrap; inf in our buffer would give inf-inf=NaN
// in the comparator).
// ---------------------------------------------------------------------------
__global__ __launch_bounds__(THREADS)
void scanscatter_kernel(const int* __restrict__ cols,
                        const float* __restrict__ rsort,
                        float* __restrict__ out) {
    __shared__ double sdata[THREADS];

    const int tid  = threadIdx.x;
    const int bh   = blockIdx.x;
    const int base = tid * CHUNK;

    // Column indices for my 16 sorted positions (latency hidden by scan below)
    int c[CHUNK];
    const int4* c4 = (const int4*)(cols + (size_t)bh * N + base);
    #pragma unroll
    for (int q = 0; q < CHUNK / 4; ++q) {
        int4 w = c4[q];
        c[q * 4 + 0] = w.x; c[q * 4 + 1] = w.y;
        c[q * 4 + 2] = w.z; c[q * 4 + 3] = w.w;
    }

    // Per-thread local inclusive prefix over CHUNK=16 positions
    const float* rs = rsort + (size_t)bh * N;
    float  v[CHUNK];
    double local[CHUNK];
    const float4* f4 = (const float4*)(rs + base);
    #pragma unroll
    for (int q = 0; q < CHUNK / 4; ++q) {
        float4 w = f4[q];
        v[q * 4 + 0] = w.x; v[q * 4 + 1] = w.y;
        v[q * 4 + 2] = w.z; v[q * 4 + 3] = w.w;
    }
    double ssum = 0.0;
    #pragma unroll
    for (int q = 0; q < CHUNK; ++q) { ssum += (double)v[q]; local[q] = ssum; }

    // Hillis-Steele inclusive scan of the 256 chunk sums -> exclusive offset
    sdata[tid] = ssum;
    __syncthreads();
    #pragma unroll
    for (int s = 1; s < THREADS; s <<= 1) {
        double y = (tid >= s) ? sdata[tid - s] : 0.0;
        __syncthreads();
        sdata[tid] += y;
        __syncthreads();
    }
    const double off = sdata[tid] - ssum;    // sum of chunk sums [0..tid)

    float* obase = out + (size_t)bh * N * N;
    #pragma unroll
    for (int q = 0; q < CHUNK; ++q) {
        int i = base + q;                    // sorted position == output row
        double cumsum = off + local[q];
        double rel    = cumsum - (double)(i + 1) * (double)v[q];
        double rank   = rel > 0.0 ? rel : 0.0;  // relu
        double ind    = (double)i - rank;
        if (ind < 0.0) ind += (double)N;     // reference's single wrap
        if (ind < 0.0) ind = 0.0;            // ref is inf here; stay finite
        obase[(size_t)i * N + c[q]] = (float)exp(ind * -10.0);
    }
}

extern "C" void kernel_launch(void* const* d_in, const int* in_sizes, int n_in,
                              void* d_out, int out_size, void* d_ws, size_t ws_size,
                              hipStream_t stream) {
    const float* ranking = (const float*)d_in[0];
    float* out = (float*)d_out;

    // Workspace layout: cols[BH*N] ints, rsort[BH*N] floats
    int*   cols  = (int*)d_ws;
    float* rsort = (float*)((char*)d_ws + sizeof(int) * (size_t)BH * N);

    rank_kernel<<<BH * PARTS, THREADS, 0, stream>>>(ranking, cols, rsort);
    zero_kernel<<<ZERO_BLOCKS, THREADS, 0, stream>>>(out);
    scanscatter_kernel<<<BH, THREADS, 0, stream>>>(cols, rsort, out);
}

// Round 4
// 532.455 us; speedup vs baseline: 1.0825x; 1.0559x over previous
//
#include <hip/hip_runtime.h>
#include <math.h>

#define N 4096
#define BH 8
#define THREADS 256
#define PARTS 32              // rank blocks per row -> BH*PARTS = 256 rank blocks
#define EPB 128               // elements ranked per block
#define EPT 4                 // elements per thread
#define SLICES 8              // key slices per row scan
#define KPS (N / SLICES)      // 512 keys per slice
#define CHUNK (N / THREADS)   // 16 sorted positions per thread in scan phase

// Monotone-descending stable composite key: ascending u64 order of
// (desc_bits(r*100) << 32 | index) == stable descending sort of r*100
// (matches reference argsort(-r*100, stable) exactly, including f32-multiply
// ties; indices are distinct so ONE u64 compare encodes the full
// lexicographic (key, index) order).
__device__ __forceinline__ unsigned long long desc_key64(float r, int i) {
    float k = r * 100.0f;
    unsigned int b = __float_as_uint(k);
    unsigned int asc = (b & 0x80000000u) ? ~b : (b | 0x80000000u);
    return ((unsigned long long)(~asc) << 32) | (unsigned int)i;
}

// ---------------------------------------------------------------------------
// Kernel 1: rank-by-counting with u64 keys (unchanged — ~10 us).
// Scatter: cols[rank] = e, rsort[rank] = r[e]  (ranks are a permutation).
// ---------------------------------------------------------------------------
__global__ __launch_bounds__(THREADS)
void rank_kernel(const float* __restrict__ ranking,
                 int* __restrict__ cols,
                 float* __restrict__ rsort) {
    __shared__ unsigned long long keys[N];               // 32 KB
    __shared__ unsigned short partial[SLICES * EPB];     // 2 KB

    const int bh   = blockIdx.x / PARTS;
    const int part = blockIdx.x % PARTS;
    const float* r = ranking + (size_t)bh * N;

    const float4* r4 = (const float4*)r;
    for (int i = threadIdx.x; i < N / 4; i += THREADS) {
        float4 w = r4[i];
        keys[i * 4 + 0] = desc_key64(w.x, i * 4 + 0);
        keys[i * 4 + 1] = desc_key64(w.y, i * 4 + 1);
        keys[i * 4 + 2] = desc_key64(w.z, i * 4 + 2);
        keys[i * 4 + 3] = desc_key64(w.w, i * 4 + 3);
    }
    __syncthreads();

    const int g = threadIdx.x & 31;
    const int s = threadIdx.x >> 5;
    const int e_base = g * EPT;

    unsigned long long mykey[EPT];
    #pragma unroll
    for (int j = 0; j < EPT; ++j)
        mykey[j] = keys[part * EPB + e_base + j];

    int cnt0 = 0, cnt1 = 0, cnt2 = 0, cnt3 = 0;
    const ulonglong2* k2 = (const ulonglong2*)(keys + s * KPS);
    #pragma unroll 4
    for (int k = 0; k < KPS / 2; ++k) {
        ulonglong2 kk = k2[k];
        cnt0 += (kk.x < mykey[0]) + (kk.y < mykey[0]);
        cnt1 += (kk.x < mykey[1]) + (kk.y < mykey[1]);
        cnt2 += (kk.x < mykey[2]) + (kk.y < mykey[2]);
        cnt3 += (kk.x < mykey[3]) + (kk.y < mykey[3]);
    }
    partial[s * EPB + e_base + 0] = (unsigned short)cnt0;
    partial[s * EPB + e_base + 1] = (unsigned short)cnt1;
    partial[s * EPB + e_base + 2] = (unsigned short)cnt2;
    partial[s * EPB + e_base + 3] = (unsigned short)cnt3;
    __syncthreads();

    if (threadIdx.x < EPB) {
        int rank = 0;
        #pragma unroll
        for (int t = 0; t < SLICES; ++t)
            rank += (int)partial[t * EPB + threadIdx.x];
        int e = part * EPB + threadIdx.x;
        size_t o = (size_t)bh * N + rank;
        cols[o]  = e;
        rsort[o] = r[e];
    }
}

// ---------------------------------------------------------------------------
// Kernel 2: scan + scatter, computed ONCE per bh row (8 blocks total).
// Per-thread f64 inclusive prefix over its 16 positions, Hillis-Steele scan
// of the 256 chunk sums, then each thread computes its 16 perm values and
// scatters them (plain dword stores; ~32K lines). Math is bit-identical to
// the R0 fused kernel: indicator clamped >= 0 BEFORE exp so arg <= 0 ->
// val in (0,1], never inf/NaN (ref overflows to +inf where indicator stays
// negative after the single +n wrap; inf in our buffer would give inf-inf=NaN
// in the comparator).
// ---------------------------------------------------------------------------
__global__ __launch_bounds__(THREADS)
void scanscatter_kernel(const int* __restrict__ cols,
                        const float* __restrict__ rsort,
                        float* __restrict__ out) {
    __shared__ double sdata[THREADS];

    const int tid  = threadIdx.x;
    const int bh   = blockIdx.x;
    const int base = tid * CHUNK;

    // Column indices for my 16 sorted positions (latency hidden by scan below)
    int c[CHUNK];
    const int4* c4 = (const int4*)(cols + (size_t)bh * N + base);
    #pragma unroll
    for (int q = 0; q < CHUNK / 4; ++q) {
        int4 w = c4[q];
        c[q * 4 + 0] = w.x; c[q * 4 + 1] = w.y;
        c[q * 4 + 2] = w.z; c[q * 4 + 3] = w.w;
    }

    // Per-thread local inclusive prefix over CHUNK=16 positions
    const float* rs = rsort + (size_t)bh * N;
    float  v[CHUNK];
    double local[CHUNK];
    const float4* f4 = (const float4*)(rs + base);
    #pragma unroll
    for (int q = 0; q < CHUNK / 4; ++q) {
        float4 w = f4[q];
        v[q * 4 + 0] = w.x; v[q * 4 + 1] = w.y;
        v[q * 4 + 2] = w.z; v[q * 4 + 3] = w.w;
    }
    double ssum = 0.0;
    #pragma unroll
    for (int q = 0; q < CHUNK; ++q) { ssum += (double)v[q]; local[q] = ssum; }

    // Hillis-Steele inclusive scan of the 256 chunk sums -> exclusive offset
    sdata[tid] = ssum;
    __syncthreads();
    #pragma unroll
    for (int s = 1; s < THREADS; s <<= 1) {
        double y = (tid >= s) ? sdata[tid - s] : 0.0;
        __syncthreads();
        sdata[tid] += y;
        __syncthreads();
    }
    const double off = sdata[tid] - ssum;    // sum of chunk sums [0..tid)

    float* obase = out + (size_t)bh * N * N;
    #pragma unroll
    for (int q = 0; q < CHUNK; ++q) {
        int i = base + q;                    // sorted position == output row
        double cumsum = off + local[q];
        double rel    = cumsum - (double)(i + 1) * (double)v[q];
        double rank   = rel > 0.0 ? rel : 0.0;  // relu
        double ind    = (double)i - rank;
        if (ind < 0.0) ind += (double)N;     // reference's single wrap
        if (ind < 0.0) ind = 0.0;            // ref is inf here; stay finite
        obase[(size_t)i * N + c[q]] = (float)exp(ind * -10.0);
    }
}

extern "C" void kernel_launch(void* const* d_in, const int* in_sizes, int n_in,
                              void* d_out, int out_size, void* d_ws, size_t ws_size,
                              hipStream_t stream) {
    const float* ranking = (const float*)d_in[0];
    float* out = (float*)d_out;

    // Workspace layout: cols[BH*N] ints, rsort[BH*N] floats
    int*   cols  = (int*)d_ws;
    float* rsort = (float*)((char*)d_ws + sizeof(int) * (size_t)BH * N);

    rank_kernel<<<BH * PARTS, THREADS, 0, stream>>>(ranking, cols, rsort);

    // Bulk zero via the rocclr fill path — the exact dispatch this capture
    // shows sustaining 6.2 TB/s on this arena (our hand-rolled fills, nt or
    // plain, plateau at ~2.8 TB/s). Stream-ordered, graph-capturable (the
    // harness's own poison is a captured fill).
    hipMemsetAsync(out, 0, sizeof(float) * (size_t)BH * N * N, stream);

    scanscatter_kernel<<<BH, THREADS, 0, stream>>>(cols, rsort, out);
}

// Round 5
// 530.040 us; speedup vs baseline: 1.0875x; 1.0046x over previous
//
#include <hip/hip_runtime.h>
#include <math.h>

#define N 4096
#define BH 8
#define THREADS 256
#define PARTS 32              // rank blocks per row -> BH*PARTS = 256 rank blocks
#define EPB 128               // elements ranked per block
#define EPT 4                 // elements per thread
#define SLICES 8              // key slices per row scan
#define KPS (N / SLICES)      // 512 keys per slice
#define CHUNK (N / THREADS)   // 16 sorted positions per thread in scan phase
#define FB 256                // fill blocks: 1/CU, 4 waves/CU (~12.5% occ, rocclr-fill shape)
#define RPF (BH * N / FB)     // 128 rows per fill block (2 MiB contiguous slice)

typedef float f32x4 __attribute__((ext_vector_type(4)));

// Monotone-descending stable composite key: ascending u64 order of
// (desc_bits(r*100) << 32 | index) == stable descending sort of r*100
// (matches reference argsort(-r*100, stable) exactly, including f32-multiply
// ties; indices are distinct so ONE u64 compare encodes the full
// lexicographic (key, index) order).
__device__ __forceinline__ unsigned long long desc_key64(float r, int i) {
    float k = r * 100.0f;
    unsigned int b = __float_as_uint(k);
    unsigned int asc = (b & 0x80000000u) ? ~b : (b | 0x80000000u);
    return ((unsigned long long)(~asc) << 32) | (unsigned int)i;
}

// ---------------------------------------------------------------------------
// Kernel 1: rank-by-counting with u64 keys (unchanged — ~10 us).
// Scatter: cols[rank] = e, rsort[rank] = r[e]  (ranks are a permutation).
// ---------------------------------------------------------------------------
__global__ __launch_bounds__(THREADS)
void rank_kernel(const float* __restrict__ ranking,
                 int* __restrict__ cols,
                 float* __restrict__ rsort) {
    __shared__ unsigned long long keys[N];               // 32 KB
    __shared__ unsigned short partial[SLICES * EPB];     // 2 KB

    const int bh   = blockIdx.x / PARTS;
    const int part = blockIdx.x % PARTS;
    const float* r = ranking + (size_t)bh * N;

    const float4* r4 = (const float4*)r;
    for (int i = threadIdx.x; i < N / 4; i += THREADS) {
        float4 w = r4[i];
        keys[i * 4 + 0] = desc_key64(w.x, i * 4 + 0);
        keys[i * 4 + 1] = desc_key64(w.y, i * 4 + 1);
        keys[i * 4 + 2] = desc_key64(w.z, i * 4 + 2);
        keys[i * 4 + 3] = desc_key64(w.w, i * 4 + 3);
    }
    __syncthreads();

    const int g = threadIdx.x & 31;
    const int s = threadIdx.x >> 5;
    const int e_base = g * EPT;

    unsigned long long mykey[EPT];
    #pragma unroll
    for (int j = 0; j < EPT; ++j)
        mykey[j] = keys[part * EPB + e_base + j];

    int cnt0 = 0, cnt1 = 0, cnt2 = 0, cnt3 = 0;
    const ulonglong2* k2 = (const ulonglong2*)(keys + s * KPS);
    #pragma unroll 4
    for (int k = 0; k < KPS / 2; ++k) {
        ulonglong2 kk = k2[k];
        cnt0 += (kk.x < mykey[0]) + (kk.y < mykey[0]);
        cnt1 += (kk.x < mykey[1]) + (kk.y < mykey[1]);
        cnt2 += (kk.x < mykey[2]) + (kk.y < mykey[2]);
        cnt3 += (kk.x < mykey[3]) + (kk.y < mykey[3]);
    }
    partial[s * EPB + e_base + 0] = (unsigned short)cnt0;
    partial[s * EPB + e_base + 1] = (unsigned short)cnt1;
    partial[s * EPB + e_base + 2] = (unsigned short)cnt2;
    partial[s * EPB + e_base + 3] = (unsigned short)cnt3;
    __syncthreads();

    if (threadIdx.x < EPB) {
        int rank = 0;
        #pragma unroll
        for (int t = 0; t < SLICES; ++t)
            rank += (int)partial[t * EPB + threadIdx.x];
        int e = part * EPB + threadIdx.x;
        size_t o = (size_t)bh * N + rank;
        cols[o]  = e;
        rsort[o] = r[e];
    }
}

// ---------------------------------------------------------------------------
// Kernel 2: scan -> per-position values, computed ONCE per bh row (8 blocks).
// Identical math to the verified scanscatter (f64 prefix, Hillis-Steele,
// indicator clamped >= 0 before exp so arg <= 0 -> val in (0,1], never
// inf/NaN where the ref overflows to +inf), but writes vals[] LINEARLY
// instead of scattering into the 512 MiB output — the scatter now happens
// inside the fill kernel for free.
// ---------------------------------------------------------------------------
__global__ __launch_bounds__(THREADS)
void scanvals_kernel(const float* __restrict__ rsort,
                     float* __restrict__ vals) {
    __shared__ double sdata[THREADS];

    const int tid  = threadIdx.x;
    const int bh   = blockIdx.x;
    const int base = tid * CHUNK;

    const float* rs = rsort + (size_t)bh * N;
    float  v[CHUNK];
    double local[CHUNK];
    const float4* f4 = (const float4*)(rs + base);
    #pragma unroll
    for (int q = 0; q < CHUNK / 4; ++q) {
        float4 w = f4[q];
        v[q * 4 + 0] = w.x; v[q * 4 + 1] = w.y;
        v[q * 4 + 2] = w.z; v[q * 4 + 3] = w.w;
    }
    double ssum = 0.0;
    #pragma unroll
    for (int q = 0; q < CHUNK; ++q) { ssum += (double)v[q]; local[q] = ssum; }

    // Hillis-Steele inclusive scan of the 256 chunk sums -> exclusive offset
    sdata[tid] = ssum;
    __syncthreads();
    #pragma unroll
    for (int s = 1; s < THREADS; s <<= 1) {
        double y = (tid >= s) ? sdata[tid - s] : 0.0;
        __syncthreads();
        sdata[tid] += y;
        __syncthreads();
    }
    const double off = sdata[tid] - ssum;    // sum of chunk sums [0..tid)

    float* vo = vals + (size_t)bh * N;
    #pragma unroll
    for (int q = 0; q < CHUNK; ++q) {
        int i = base + q;                    // sorted position == output row
        double cumsum = off + local[q];
        double rel    = cumsum - (double)(i + 1) * (double)v[q];
        double rank   = rel > 0.0 ? rel : 0.0;  // relu
        double ind    = (double)i - rank;
        if (ind < 0.0) ind += (double)N;     // reference's single wrap
        if (ind < 0.0) ind = 0.0;            // ref is inf here; stay finite
        vo[i] = (float)exp(ind * -10.0);
    }
}

// ---------------------------------------------------------------------------
// Kernel 3: fill + inject. 256 blocks (1/CU, 4 waves/CU ~= the 10% occupancy
// at which rocclr's fill measures 6.2 TB/s in this capture; our previous
// 2048-block/100%-occ fills all plateaued at 2.6-3.3 TB/s). Each block
// streams a contiguous 2 MiB slice (128 output rows) with plain float4
// stores and injects each row's single nonzero in-line via a predicated
// store (R0's verified pattern). (col,val) pairs staged once in LDS;
// 1 broadcast ds_read pair per 4 stores. No separate scatter kernel, no
// race: the same store that would write zero writes the value instead.
// ---------------------------------------------------------------------------
__global__ __launch_bounds__(THREADS)
void fillinject_kernel(const int* __restrict__ cols,
                       const float* __restrict__ vals,
                       float* __restrict__ out) {
    __shared__ int   sc[RPF];
    __shared__ float sv[RPF];

    const int tid = threadIdx.x;
    const size_t g0 = (size_t)blockIdx.x * RPF;      // first global output row

    for (int i = tid; i < RPF; i += THREADS) {
        sc[i] = cols[g0 + i];
        sv[i] = vals[g0 + i];
    }
    __syncthreads();

    f32x4* o = (f32x4*)(out + g0 * N);
    // 128 rows x 1024 float4 = 131072 float4 per block; 4 wave-sweeps per row
    #pragma unroll 1
    for (int kk = 0; kk < (RPF * (N / 4)) / THREADS; kk += 4) {
        const int   row  = kk >> 2;
        const int   c    = sc[row];          // broadcast: conflict-free
        const float v    = sv[row];
        const int   fc   = c >> 2;           // float4 index within row
        const int   lane = c & 3;
        #pragma unroll
        for (int q = 0; q < 4; ++q) {
            int idx_in_row = (q << 8) | tid; // 0..1023
            f32x4 w = {0.f, 0.f, 0.f, 0.f};
            if (idx_in_row == fc) w[lane] = v;
            o[(size_t)(kk + q) * THREADS + tid] = w;
        }
    }
}

extern "C" void kernel_launch(void* const* d_in, const int* in_sizes, int n_in,
                              void* d_out, int out_size, void* d_ws, size_t ws_size,
                              hipStream_t stream) {
    const float* ranking = (const float*)d_in[0];
    float* out = (float*)d_out;

    // Workspace layout: cols[BH*N] ints, rsort[BH*N] floats, vals[BH*N] floats
    int*   cols  = (int*)d_ws;
    float* rsort = (float*)((char*)d_ws + sizeof(int) * (size_t)BH * N);
    float* vals  = (float*)((char*)d_ws + (sizeof(int) + sizeof(float)) * (size_t)BH * N);

    rank_kernel<<<BH * PARTS, THREADS, 0, stream>>>(ranking, cols, rsort);
    scanvals_kernel<<<BH, THREADS, 0, stream>>>(rsort, vals);
    fillinject_kernel<<<FB, THREADS, 0, stream>>>(cols, vals, out);
}

// Round 7
// 527.516 us; speedup vs baseline: 1.0927x; 1.0048x over previous
//
#include <hip/hip_runtime.h>
#include <math.h>

#define N 4096
#define BH 8
#define THREADS 256
#define PARTS 32              // rank blocks per row -> BH*PARTS = 256 rank blocks
#define EPB 128               // elements ranked per block
#define EPT 4                 // elements per thread
#define SLICES 8              // key slices per row scan
#define KPS (N / SLICES)      // 512 keys per slice
#define CHUNK (N / THREADS)   // 16 sorted positions per thread in scan phase
#define Z1_BLOCKS 131072      // (BH*N*N/4) / THREADS: ONE float4 store per thread

typedef float f32x4 __attribute__((ext_vector_type(4)));

// Monotone-descending stable composite key: ascending u64 order of
// (desc_bits(r*100) << 32 | index) == stable descending sort of r*100
// (matches reference argsort(-r*100, stable) exactly, including f32-multiply
// ties; indices are distinct so ONE u64 compare encodes the full
// lexicographic (key, index) order).
__device__ __forceinline__ unsigned long long desc_key64(float r, int i) {
    float k = r * 100.0f;
    unsigned int b = __float_as_uint(k);
    unsigned int asc = (b & 0x80000000u) ? ~b : (b | 0x80000000u);
    return ((unsigned long long)(~asc) << 32) | (unsigned int)i;
}

// ---------------------------------------------------------------------------
// Kernel 1: rank-by-counting with u64 keys (unchanged — ~10 us).
// Scatter: cols[rank] = e, rsort[rank] = r[e]  (ranks are a permutation).
// ---------------------------------------------------------------------------
__global__ __launch_bounds__(THREADS)
void rank_kernel(const float* __restrict__ ranking,
                 int* __restrict__ cols,
                 float* __restrict__ rsort) {
    __shared__ unsigned long long keys[N];               // 32 KB
    __shared__ unsigned short partial[SLICES * EPB];     // 2 KB

    const int bh   = blockIdx.x / PARTS;
    const int part = blockIdx.x % PARTS;
    const float* r = ranking + (size_t)bh * N;

    const float4* r4 = (const float4*)r;
    for (int i = threadIdx.x; i < N / 4; i += THREADS) {
        float4 w = r4[i];
        keys[i * 4 + 0] = desc_key64(w.x, i * 4 + 0);
        keys[i * 4 + 1] = desc_key64(w.y, i * 4 + 1);
        keys[i * 4 + 2] = desc_key64(w.z, i * 4 + 2);
        keys[i * 4 + 3] = desc_key64(w.w, i * 4 + 3);
    }
    __syncthreads();

    const int g = threadIdx.x & 31;
    const int s = threadIdx.x >> 5;
    const int e_base = g * EPT;

    unsigned long long mykey[EPT];
    #pragma unroll
    for (int j = 0; j < EPT; ++j)
        mykey[j] = keys[part * EPB + e_base + j];

    int cnt0 = 0, cnt1 = 0, cnt2 = 0, cnt3 = 0;
    const ulonglong2* k2 = (const ulonglong2*)(keys + s * KPS);
    #pragma unroll 4
    for (int k = 0; k < KPS / 2; ++k) {
        ulonglong2 kk = k2[k];
        cnt0 += (kk.x < mykey[0]) + (kk.y < mykey[0]);
        cnt1 += (kk.x < mykey[1]) + (kk.y < mykey[1]);
        cnt2 += (kk.x < mykey[2]) + (kk.y < mykey[2]);
        cnt3 += (kk.x < mykey[3]) + (kk.y < mykey[3]);
    }
    partial[s * EPB + e_base + 0] = (unsigned short)cnt0;
    partial[s * EPB + e_base + 1] = (unsigned short)cnt1;
    partial[s * EPB + e_base + 2] = (unsigned short)cnt2;
    partial[s * EPB + e_base + 3] = (unsigned short)cnt3;
    __syncthreads();

    if (threadIdx.x < EPB) {
        int rank = 0;
        #pragma unroll
        for (int t = 0; t < SLICES; ++t)
            rank += (int)partial[t * EPB + threadIdx.x];
        int e = part * EPB + threadIdx.x;
        size_t o = (size_t)bh * N + rank;
        cols[o]  = e;
        rsort[o] = r[e];
    }
}

// ---------------------------------------------------------------------------
// Kernel 2: rocclr-shape zero fill — ONE float4 store per thread, massive
// grid, no loop, no LDS, minimal VGPRs. The 6.2 TB/s fillBufferAligned in
// every capture reports 10% occupancy @ 8 VGPR: blocks retire instantly,
// residency limited by dispatch rate — i.e. it's a one-shot-store shape,
// not a resident loop. Every looped fill we wrote capped at 2.6-3.3 TB/s;
// this is the exact-shape A/B.
// ---------------------------------------------------------------------------
__global__ __launch_bounds__(THREADS)
void zero1_kernel(float* __restrict__ out) {
    f32x4 z = {0.f, 0.f, 0.f, 0.f};
    size_t i = (size_t)blockIdx.x * THREADS + threadIdx.x;
    ((f32x4*)out)[i] = z;
}

// ---------------------------------------------------------------------------
// Kernel 3: scan + scatter, ONCE per bh row (8 blocks, ~15 us). Verified in
// R3/R4. f64 prefix, Hillis-Steele, indicator clamped >= 0 before exp so
// arg <= 0 -> val in (0,1], never inf/NaN (ref overflows to +inf where
// indicator stays negative after the single +n wrap; inf in our buffer
// would give inf-inf=NaN in the comparator).
// ---------------------------------------------------------------------------
__global__ __launch_bounds__(THREADS)
void scanscatter_kernel(const int* __restrict__ cols,
                        const float* __restrict__ rsort,
                        float* __restrict__ out) {
    __shared__ double sdata[THREADS];

    const int tid  = threadIdx.x;
    const int bh   = blockIdx.x;
    const int base = tid * CHUNK;

    // Column indices for my 16 sorted positions (latency hidden by scan below)
    int c[CHUNK];
    const int4* c4 = (const int4*)(cols + (size_t)bh * N + base);
    #pragma unroll
    for (int q = 0; q < CHUNK / 4; ++q) {
        int4 w = c4[q];
        c[q * 4 + 0] = w.x; c[q * 4 + 1] = w.y;
        c[q * 4 + 2] = w.z; c[q * 4 + 3] = w.w;
    }

    // Per-thread local inclusive prefix over CHUNK=16 positions
    const float* rs = rsort + (size_t)bh * N;
    float  v[CHUNK];
    double local[CHUNK];
    const float4* f4 = (const float4*)(rs + base);
    #pragma unroll
    for (int q = 0; q < CHUNK / 4; ++q) {
        float4 w = f4[q];
        v[q * 4 + 0] = w.x; v[q * 4 + 1] = w.y;
        v[q * 4 + 2] = w.z; v[q * 4 + 3] = w.w;
    }
    double ssum = 0.0;
    #pragma unroll
    for (int q = 0; q < CHUNK; ++q) { ssum += (double)v[q]; local[q] = ssum; }

    // Hillis-Steele inclusive scan of the 256 chunk sums -> exclusive offset
    sdata[tid] = ssum;
    __syncthreads();
    #pragma unroll
    for (int s = 1; s < THREADS; s <<= 1) {
        double y = (tid >= s) ? sdata[tid - s] : 0.0;
        __syncthreads();
        sdata[tid] += y;
        __syncthreads();
    }
    const double off = sdata[tid] - ssum;    // sum of chunk sums [0..tid)

    float* obase = out + (size_t)bh * N * N;
    #pragma unroll
    for (int q = 0; q < CHUNK; ++q) {
        int i = base + q;                    // sorted position == output row
        double cumsum = off + local[q];
        double rel    = cumsum - (double)(i + 1) * (double)v[q];
        double rank   = rel > 0.0 ? rel : 0.0;  // relu
        double ind    = (double)i - rank;
        if (ind < 0.0) ind += (double)N;     // reference's single wrap
        if (ind < 0.0) ind = 0.0;            // ref is inf here; stay finite
        obase[(size_t)i * N + c[q]] = (float)exp(ind * -10.0);
    }
}

extern "C" void kernel_launch(void* const* d_in, const int* in_sizes, int n_in,
                              void* d_out, int out_size, void* d_ws, size_t ws_size,
                              hipStream_t stream) {
    const float* ranking = (const float*)d_in[0];
    float* out = (float*)d_out;

    // Workspace layout: cols[BH*N] ints, rsort[BH*N] floats
    int*   cols  = (int*)d_ws;
    float* rsort = (float*)((char*)d_ws + sizeof(int) * (size_t)BH * N);

    rank_kernel<<<dim3(BH * PARTS), dim3(THREADS), 0, stream>>>(ranking, cols, rsort);
    zero1_kernel<<<dim3(Z1_BLOCKS), dim3(THREADS), 0, stream>>>(out);
    scanscatter_kernel<<<dim3(BH), dim3(THREADS), 0, stream>>>(cols, rsort, out);
}